// Round 9
// baseline (377.804 us; speedup 1.0000x reference)
//
#include <hip/hip_runtime.h>
#include <math.h>

// ============================================================================
// MEASUREMENT PROBE ROUND: pass A executed 4x (finalize scales by 0.25).
//   - dur delta vs R3 (274.75us) = 3 * A_time  -> direct A measurement
//   - fused kernel becomes >163us -> appears in rocprof top-5 WITH counters
// Next round reverts to single-pass A.
// ============================================================================

#define N_PTS 8192
#define TPB 256
#define RPB 4
#define A_PASSES 4   // PROBE: 4 sweeps, finalize * 0.25f

// constants
#define C_LAMBDA   2.5f
#define C_REPEL    0.15f
#define C_EPS      0.1f
#define C_NORM_EPS 1e-8f
#define C_TAUW     0.3f
#define C_TWO_PI   6.28318530717958647692f
#define C_NEG_L_LOG2E (-3.60673760222240625f)   // -2.5 * log2(e)
#define C_Q_DELTA  1e-16f   // rsqrt guard: q==0 (diagonal) stays finite

typedef float vf4 __attribute__((ext_vector_type(4)));

__device__ __forceinline__ float fast_exp2(float x) {
#if __has_builtin(__builtin_amdgcn_exp2f)
    return __builtin_amdgcn_exp2f(x);
#else
    return exp2f(x);
#endif
}
__device__ __forceinline__ float fast_rsqrt(float x) {
#if __has_builtin(__builtin_amdgcn_rsqf)
    return __builtin_amdgcn_rsqf(x);
#else
    return rsqrtf(x);
#endif
}
__device__ __forceinline__ float fast_log2(float x) {
#if __has_builtin(__builtin_amdgcn_logf)
    return __builtin_amdgcn_logf(x);   // v_log_f32 = log2
#else
    return log2f(x);
#endif
}

__device__ __forceinline__ float wave_reduce_sum(float v) {
    #pragma unroll
    for (int off = 32; off > 0; off >>= 1)
        v += __shfl_down(v, off, 64);
    return v;
}

// Pack j-stream: pk[j] = {theta, tau, cos, sin}; pk2[j] = {theta, tau}
__global__ void pack_kernel(const float* __restrict__ theta,
                            const float* __restrict__ tau,
                            float4* __restrict__ pk,
                            float2* __restrict__ pk2) {
    int i = blockIdx.x * blockDim.x + threadIdx.x;
    float t = theta[i];
    float u = tau[i];
    pk[i]  = make_float4(t, u, cosf(t), sinf(t));
    pk2[i] = make_float2(t, u);
}

__global__ __launch_bounds__(TPB) void fused_kernel(
    const float4* __restrict__ pk,
    const float4* __restrict__ pq,   // (float4*)pk2: {th(2m),ta(2m),th(2m+1),ta(2m+1)}
    float* __restrict__ out)         // [theta_out(N) | tau_out(N) | attn(N*N)]
{
    const int tid  = threadIdx.x;
    const int row0 = blockIdx.x * RPB;

    float th_i[RPB], ta_i[RPB], c_i[RPB], s_i[RPB];
    #pragma unroll
    for (int r = 0; r < RPB; ++r) {
        float4 p = pk[row0 + r];
        th_i[r] = p.x; ta_i[r] = p.y; c_i[r] = p.z; s_i[r] = p.w;
    }

    float a_sum[RPB], a_x[RPB], a_y[RPB], a_t[RPB], rp_x[RPB], rp_y[RPB];
    #pragma unroll
    for (int r = 0; r < RPB; ++r) {
        a_sum[r] = 0.f; a_x[r] = 0.f; a_y[r] = 0.f;
        a_t[r] = 0.f; rp_x[r] = 0.f; rp_y[r] = 0.f;
    }

    // ---- pass A (x A_PASSES, probe): j-sweep; compiler-scheduled loads ----
    // diagonal flows through (score=1 at j==i; repulsion self-term is exactly
    // 0 since dx=dy=0 and rsqrt stays finite via C_Q_DELTA); attention
    // self-contribution is subtracted in the finalize step after 1/A_PASSES
    // rescale (each pass contributes one diagonal score of 1).
    #pragma unroll 1
    for (int pass = 0; pass < A_PASSES; ++pass) {
        #pragma unroll 4
        for (int k = 0; k < N_PTS / TPB; ++k) {
            float4 cur = pk[tid + k * TPB];
            #pragma unroll
            for (int r = 0; r < RPB; ++r) {
                float ad    = fabsf(th_i[r] - cur.x);
                float dth   = fminf(ad, C_TWO_PI - ad);
                float t     = fmaf(fabsf(ta_i[r] - cur.y), C_TAUW, dth);
                float score = fast_exp2(t * C_NEG_L_LOG2E);
                a_sum[r] += score;
                a_x[r]   = fmaf(score, cur.z, a_x[r]);
                a_y[r]   = fmaf(score, cur.w, a_y[r]);
                a_t[r]   = fmaf(score, cur.y, a_t[r]);

                float d   = dth + C_EPS;
                float dx  = c_i[r] - cur.z;
                float dy  = s_i[r] - cur.w;
                float q   = fmaf(dx, dx, dy * dy);
                float d2  = d * d;
                float inv = fast_rsqrt((q + C_Q_DELTA) * (d2 * d2));
                rp_x[r] = fmaf(inv, dx, rp_x[r]);
                rp_y[r] = fmaf(inv, dy, rp_y[r]);
            }
        }
    }

    __shared__ float red[RPB][6][TPB / 64];
    __shared__ float l2s[RPB];
    const int wave = tid >> 6;
    const int lane = tid & 63;
    #pragma unroll
    for (int r = 0; r < RPB; ++r) {
        float v0 = wave_reduce_sum(a_sum[r]);
        float v1 = wave_reduce_sum(a_x[r]);
        float v2 = wave_reduce_sum(a_y[r]);
        float v3 = wave_reduce_sum(a_t[r]);
        float v4 = wave_reduce_sum(rp_x[r]);
        float v5 = wave_reduce_sum(rp_y[r]);
        if (lane == 0) {
            red[r][0][wave] = v0; red[r][1][wave] = v1; red[r][2][wave] = v2;
            red[r][3][wave] = v3; red[r][4][wave] = v4; red[r][5][wave] = v5;
        }
    }
    __syncthreads();

    if (tid < RPB) {
        const int r = tid;
        float s = 0.f, x = 0.f, y = 0.f, t = 0.f, rx = 0.f, ry = 0.f;
        #pragma unroll
        for (int w = 0; w < TPB / 64; ++w) {
            s  += red[r][0][w]; x  += red[r][1][w]; y  += red[r][2][w];
            t  += red[r][3][w]; rx += red[r][4][w]; ry += red[r][5][w];
        }
        // PROBE: rescale the A_PASSES-fold accumulation back to one pass
        const float inv_p = 1.0f / (float)A_PASSES;
        s *= inv_p; x *= inv_p; y *= inv_p; t *= inv_p; rx *= inv_p; ry *= inv_p;
        // subtract the j==i attention self-contribution (score == 1)
        float4 p = pk[row0 + r];
        s -= 1.0f;
        x -= p.z;
        y -= p.w;
        t -= p.y;
        float invr = 1.0f / s;
        float fx = fmaf(x, invr, C_REPEL * rx);
        float fy = fmaf(y, invr, C_REPEL * ry);
        out[row0 + r]         = atan2f(fy, fx);   // theta_out
        out[N_PTS + row0 + r] = t * invr;         // tau_out
        l2s[r] = fast_log2(invr);                 // fold normalization into exp2
    }
    __syncthreads();

    // ---- pass B: write normalized attn rows, 4 j's per thread, float4 stores ----
    float l2r[RPB];
    #pragma unroll
    for (int r = 0; r < RPB; ++r) l2r[r] = l2s[r];

    float* __restrict__ attn = out + 2 * N_PTS;

    #pragma unroll 2
    for (int k = 0; k < N_PTS / (TPB * 4); ++k) {
        const int base = tid + k * TPB;       // pair-of-float2 quad index
        float4 f1 = pq[2 * base];             // j0, j0+1
        float4 f2 = pq[2 * base + 1];         // j0+2, j0+3
        const int j0 = 4 * base;
        #pragma unroll
        for (int r = 0; r < RPB; ++r) {
            float ad0  = fabsf(th_i[r] - f1.x);
            float dth0 = fminf(ad0, C_TWO_PI - ad0);
            float t0   = fmaf(fabsf(ta_i[r] - f1.y), C_TAUW, dth0);
            float v0   = fast_exp2(fmaf(t0, C_NEG_L_LOG2E, l2r[r]));

            float ad1  = fabsf(th_i[r] - f1.z);
            float dth1 = fminf(ad1, C_TWO_PI - ad1);
            float t1   = fmaf(fabsf(ta_i[r] - f1.w), C_TAUW, dth1);
            float v1   = fast_exp2(fmaf(t1, C_NEG_L_LOG2E, l2r[r]));

            float ad2  = fabsf(th_i[r] - f2.x);
            float dth2 = fminf(ad2, C_TWO_PI - ad2);
            float t2   = fmaf(fabsf(ta_i[r] - f2.y), C_TAUW, dth2);
            float v2   = fast_exp2(fmaf(t2, C_NEG_L_LOG2E, l2r[r]));

            float ad3  = fabsf(th_i[r] - f2.z);
            float dth3 = fminf(ad3, C_TWO_PI - ad3);
            float t3   = fmaf(fabsf(ta_i[r] - f2.w), C_TAUW, dth3);
            float v3   = fast_exp2(fmaf(t3, C_NEG_L_LOG2E, l2r[r]));

            vf4 o = {v0, v1, v2, v3};
            *(vf4*)(attn + (size_t)(row0 + r) * N_PTS + j0) = o;
        }
    }

    // diagonal: overwrite attn[i][i] = 0 after all row stores (workgroup fence)
    __syncthreads();
    if (tid < RPB) {
        const int i = row0 + tid;
        attn[(size_t)i * N_PTS + i] = 0.0f;
    }
}

extern "C" void kernel_launch(void* const* d_in, const int* in_sizes, int n_in,
                              void* d_out, int out_size, void* d_ws, size_t ws_size,
                              hipStream_t stream) {
    const float* theta = (const float*)d_in[0];
    const float* tau   = (const float*)d_in[1];

    float4* pk  = (float4*)d_ws;                          // 128 KB
    float2* pk2 = (float2*)((char*)d_ws + 128 * 1024);    //  64 KB
    float*  out = (float*)d_out;

    pack_kernel<<<N_PTS / 256, 256, 0, stream>>>(theta, tau, pk, pk2);
    fused_kernel<<<N_PTS / RPB, TPB, 0, stream>>>(pk, (const float4*)pk2, out);
}

// Round 10
// 279.019 us; speedup vs baseline: 1.3540x; 1.3540x over previous
//
#include <hip/hip_runtime.h>
#include <math.h>

#define N_PTS 8192
#define TPB 256
#define RPB 4
// Measured (R9 probe): A = 34us (VALUBusy 90% -> at issue ceiling),
// B = 58us vs 41us drain floor (268MB @ 6.6TB/s). FETCH ~2.4MB (inputs
// cache-resident). R8: loads in B are harmless (vmcnt theory null).
// This round: pass B r-outer -> each block writes ONE contiguous ascending
// 128KB region (fill-like) instead of interleaving 4 rows 32KB apart.
// Store-order-only change: output bits identical to R3.

// constants
#define C_LAMBDA   2.5f
#define C_REPEL    0.15f
#define C_EPS      0.1f
#define C_NORM_EPS 1e-8f
#define C_TAUW     0.3f
#define C_TWO_PI   6.28318530717958647692f
#define C_NEG_L_LOG2E (-3.60673760222240625f)   // -2.5 * log2(e)
#define C_Q_DELTA  1e-16f   // rsqrt guard: q==0 (diagonal) stays finite

typedef float vf4 __attribute__((ext_vector_type(4)));

__device__ __forceinline__ float fast_exp2(float x) {
#if __has_builtin(__builtin_amdgcn_exp2f)
    return __builtin_amdgcn_exp2f(x);
#else
    return exp2f(x);
#endif
}
__device__ __forceinline__ float fast_rsqrt(float x) {
#if __has_builtin(__builtin_amdgcn_rsqf)
    return __builtin_amdgcn_rsqf(x);
#else
    return rsqrtf(x);
#endif
}
__device__ __forceinline__ float fast_log2(float x) {
#if __has_builtin(__builtin_amdgcn_logf)
    return __builtin_amdgcn_logf(x);   // v_log_f32 = log2
#else
    return log2f(x);
#endif
}

__device__ __forceinline__ float wave_reduce_sum(float v) {
    #pragma unroll
    for (int off = 32; off > 0; off >>= 1)
        v += __shfl_down(v, off, 64);
    return v;
}

// pass-B: one normalized attention value (theta_j, tau_j) vs uniform row (thb, tab, l2b)
#define B_VAL(THJ, TAJ, THB, TAB, L2B, V) do {                             \
    float ad  = fabsf((THB) - (THJ));                                      \
    float dth = fminf(ad, C_TWO_PI - ad);                                  \
    float t   = fmaf(fabsf((TAB) - (TAJ)), C_TAUW, dth);                   \
    (V) = fast_exp2(fmaf(t, C_NEG_L_LOG2E, (L2B)));                        \
} while (0)

// Pack j-stream: pk[j] = {theta, tau, cos, sin}; pk2[j] = {theta, tau}
__global__ void pack_kernel(const float* __restrict__ theta,
                            const float* __restrict__ tau,
                            float4* __restrict__ pk,
                            float2* __restrict__ pk2) {
    int i = blockIdx.x * blockDim.x + threadIdx.x;
    float t = theta[i];
    float u = tau[i];
    pk[i]  = make_float4(t, u, cosf(t), sinf(t));
    pk2[i] = make_float2(t, u);
}

// Fused: pass A = per-row reductions (theta_out, tau_out, invsum);
//        pass B = normalized attn writeback, r-outer contiguous streaming.
__global__ __launch_bounds__(TPB) void fused_kernel(
    const float4* __restrict__ pk,
    const float4* __restrict__ pq,   // (float4*)pk2: {th(2m),ta(2m),th(2m+1),ta(2m+1)}
    float* __restrict__ out)         // [theta_out(N) | tau_out(N) | attn(N*N)]
{
    const int tid  = threadIdx.x;
    const int row0 = blockIdx.x * RPB;

    float th_i[RPB], ta_i[RPB], c_i[RPB], s_i[RPB];
    #pragma unroll
    for (int r = 0; r < RPB; ++r) {
        float4 p = pk[row0 + r];
        th_i[r] = p.x; ta_i[r] = p.y; c_i[r] = p.z; s_i[r] = p.w;
    }

    float a_sum[RPB], a_x[RPB], a_y[RPB], a_t[RPB], rp_x[RPB], rp_y[RPB];
    #pragma unroll
    for (int r = 0; r < RPB; ++r) {
        a_sum[r] = 0.f; a_x[r] = 0.f; a_y[r] = 0.f;
        a_t[r] = 0.f; rp_x[r] = 0.f; rp_y[r] = 0.f;
    }

    // ---- pass A: j-sweep; compiler-scheduled loads (at VALU ceiling) ----
    // diagonal flows through (score=1 at j==i; repulsion self-term is exactly
    // 0 since dx=dy=0 and rsqrt stays finite via C_Q_DELTA); attention
    // self-contribution is subtracted in the finalize step.
    #pragma unroll 4
    for (int k = 0; k < N_PTS / TPB; ++k) {
        float4 cur = pk[tid + k * TPB];
        #pragma unroll
        for (int r = 0; r < RPB; ++r) {
            float ad    = fabsf(th_i[r] - cur.x);
            float dth   = fminf(ad, C_TWO_PI - ad);
            float t     = fmaf(fabsf(ta_i[r] - cur.y), C_TAUW, dth);
            float score = fast_exp2(t * C_NEG_L_LOG2E);
            a_sum[r] += score;
            a_x[r]   = fmaf(score, cur.z, a_x[r]);
            a_y[r]   = fmaf(score, cur.w, a_y[r]);
            a_t[r]   = fmaf(score, cur.y, a_t[r]);

            float d   = dth + C_EPS;
            float dx  = c_i[r] - cur.z;
            float dy  = s_i[r] - cur.w;
            float q   = fmaf(dx, dx, dy * dy);
            float d2  = d * d;
            // 1/(d^2*(sqrt(q)+1e-8)) ~= rsqrt((q+delta)*d^4): one trans op
            // (trans ops calibrated ~13 cyc/wave64 on gfx950 -> minimize).
            float inv = fast_rsqrt((q + C_Q_DELTA) * (d2 * d2));
            rp_x[r] = fmaf(inv, dx, rp_x[r]);
            rp_y[r] = fmaf(inv, dy, rp_y[r]);
        }
    }

    __shared__ float red[RPB][6][TPB / 64];
    __shared__ float l2s[RPB];
    const int wave = tid >> 6;
    const int lane = tid & 63;
    #pragma unroll
    for (int r = 0; r < RPB; ++r) {
        float v0 = wave_reduce_sum(a_sum[r]);
        float v1 = wave_reduce_sum(a_x[r]);
        float v2 = wave_reduce_sum(a_y[r]);
        float v3 = wave_reduce_sum(a_t[r]);
        float v4 = wave_reduce_sum(rp_x[r]);
        float v5 = wave_reduce_sum(rp_y[r]);
        if (lane == 0) {
            red[r][0][wave] = v0; red[r][1][wave] = v1; red[r][2][wave] = v2;
            red[r][3][wave] = v3; red[r][4][wave] = v4; red[r][5][wave] = v5;
        }
    }
    __syncthreads();

    if (tid < RPB) {
        const int r = tid;
        float s = 0.f, x = 0.f, y = 0.f, t = 0.f, rx = 0.f, ry = 0.f;
        #pragma unroll
        for (int w = 0; w < TPB / 64; ++w) {
            s  += red[r][0][w]; x  += red[r][1][w]; y  += red[r][2][w];
            t  += red[r][3][w]; rx += red[r][4][w]; ry += red[r][5][w];
        }
        // subtract the j==i attention self-contribution (score == 1)
        float4 p = pk[row0 + r];
        s -= 1.0f;
        x -= p.z;
        y -= p.w;
        t -= p.y;
        float invr = 1.0f / s;
        float fx = fmaf(x, invr, C_REPEL * rx);
        float fy = fmaf(y, invr, C_REPEL * ry);
        out[row0 + r]         = atan2f(fy, fx);   // theta_out
        out[N_PTS + row0 + r] = t * invr;         // tau_out
        l2s[r] = fast_log2(invr);                 // fold normalization into exp2
    }
    __syncthreads();

    // ---- pass B: r-outer. Block streams ONE contiguous ascending 128KB
    // region (rows row0..row0+3 are adjacent in attn), like the fill kernel.
    // r-inner (R3) interleaved 4 streams 32KB apart per block -> DRAM page
    // thrash suspected as B's 58us-vs-41us-floor gap. ----
    float l2r[RPB];
    #pragma unroll
    for (int r = 0; r < RPB; ++r) l2r[r] = l2s[r];

    float* __restrict__ attn = out + 2 * N_PTS;

    #pragma unroll 1
    for (int r = 0; r < RPB; ++r) {
        const float thb = th_i[r];
        const float tab = ta_i[r];
        const float l2b = l2r[r];
        float* __restrict__ rowp = attn + (size_t)(row0 + r) * N_PTS;
        #pragma unroll 2
        for (int k = 0; k < N_PTS / (TPB * 4); ++k) {
            const int base = tid + k * TPB;       // pair-of-float2 quad index
            float4 f1 = pq[2 * base];             // j0, j0+1
            float4 f2 = pq[2 * base + 1];         // j0+2, j0+3
            float v0, v1, v2, v3;
            B_VAL(f1.x, f1.y, thb, tab, l2b, v0);
            B_VAL(f1.z, f1.w, thb, tab, l2b, v1);
            B_VAL(f2.x, f2.y, thb, tab, l2b, v2);
            B_VAL(f2.z, f2.w, thb, tab, l2b, v3);
            vf4 o = {v0, v1, v2, v3};
            *(vf4*)(rowp + 4 * base) = o;
        }
    }

    // diagonal: overwrite attn[i][i] = 0 after all row stores (workgroup fence)
    __syncthreads();
    if (tid < RPB) {
        const int i = row0 + tid;
        attn[(size_t)i * N_PTS + i] = 0.0f;
    }
}

extern "C" void kernel_launch(void* const* d_in, const int* in_sizes, int n_in,
                              void* d_out, int out_size, void* d_ws, size_t ws_size,
                              hipStream_t stream) {
    const float* theta = (const float*)d_in[0];
    const float* tau   = (const float*)d_in[1];

    float4* pk  = (float4*)d_ws;                          // 128 KB
    float2* pk2 = (float2*)((char*)d_ws + 128 * 1024);    //  64 KB
    float*  out = (float*)d_out;

    pack_kernel<<<N_PTS / 256, 256, 0, stream>>>(theta, tau, pk, pk2);
    fused_kernel<<<N_PTS / RPB, TPB, 0, stream>>>(pk, (const float4*)pk2, out);
}